// Round 17
// baseline (46.586 us; speedup 1.0000x reference)
//
#include <hip/hip_runtime.h>
#include <hip/hip_bf16.h>

#define BTOT 128     // B*T
#define NN   512
#define FIN  128
#define FOUT 64

typedef __attribute__((ext_vector_type(8))) short bf16x8;
typedef __attribute__((ext_vector_type(4))) float f32x4;

static __device__ inline ushort f2bf(float f) {
    __hip_bfloat16 h = __float2bfloat16(f);
    return *(ushort*)&h;
}
static __device__ inline float bf2f(ushort u) {
    uint v = (uint)u << 16;
    return __uint_as_float(v);
}

// async global->LDS, 16B per lane: LDS dest = wave-uniform base + lane*16,
// global src = per-lane address (pre-swizzled).
static __device__ inline void gll16(const ushort* gsrc, ushort* ldst) {
    __builtin_amdgcn_global_load_lds(
        (const __attribute__((address_space(1))) uint*)gsrc,
        (__attribute__((address_space(3))) uint*)ldst, 16, 0, 0);
}

// ---------- P: prep W split (blocks 256..287) + cd pack (blocks 0..255) ----------
// cd ushort: bits15..1 = w*log2e RNE to 7-bit mantissa; bit0 = "p nonzero".
// p = m ? exp2(c * leaky(s)) : 0 reproduces every ref corner case (see R7).
// cd stored PRE-SWIZZLED to MFMA A-frag order (per-lane 16B at base+lane*16).
__global__ void k_prep(const float* __restrict__ W, const int* __restrict__ adj,
                       const float* __restrict__ we, ushort* __restrict__ Whi,
                       ushort* __restrict__ Wlo, ushort* __restrict__ cds) {
    int b = blockIdx.x;
    if (b >= 256) {       // W split: 8192 elems over 32 blocks
        int i = (b - 256) * 256 + threadIdx.x;
        float w = W[i];
        ushort hi = f2bf(w);
        Whi[i] = hi;
        Wlo[i] = f2bf(w - bf2f(hi));
        return;
    }
    int lin = (b * 256 + threadIdx.x) * 4;   // 262144 edges, 4 consecutive j
    int i = lin >> 9, j0 = lin & 511;
    int4   a4 = *(const int4*)&adj[lin];
    float4 w4 = *(const float4*)&we[lin];
    ushort o[4];
#pragma unroll
    for (int e = 0; e < 4; ++e) {
        bool  cn = ((const int*)&a4)[e] > 0;
        float w  = ((const float*)&w4)[e];
        if (cn) {
            uint ub = __float_as_uint(w * 1.44269504f);
            uint tt = ub + 0xFFFFu + ((ub >> 17) & 1u);       // RNE @ 7-bit mantissa
            o[e] = (ushort)(((tt >> 17) << 1) | 1u);
        } else {
            o[e] = (w > 0.f) ? (ushort)0 : (ushort)1;         // p=0 | p=1
        }
    }
    // swizzled target (4 consecutive j share h,f,kc; e = j&7 runs 0..3 or 4..7)
    int swz = ((((i >> 4) * 2 + (j0 >> 8)) * 8 + ((j0 >> 5) & 7)) << 9)
            + (((j0 >> 3) & 3) << 7) + ((i & 15) << 3) + (j0 & 7);
    *(uint2*)&cds[swz] = *(uint2*)&o[0];
}

// ---------- A: h = x @ W^T via bf16x3 MFMA; emit ht bf16 [bt][o][n], src, dst ----
// 1D grid 1024, bid = ntile*128 + bt  =>  XCD = bt%8 (same XCD k_attn reads from).
__global__ void k_feat(const float* __restrict__ x, const ushort* __restrict__ Whi,
                       const ushort* __restrict__ Wlo, const float* __restrict__ a,
                       ushort* __restrict__ ht, float* __restrict__ srcv,
                       float* __restrict__ dstv) {
    const int t    = threadIdx.x;
    const int bid  = blockIdx.x;
    const int bt   = bid & 127;
    const int nt   = bid >> 7;
    const int wv   = t >> 6, lane = t & 63;
    const int r    = lane & 15;          // A-row / B-col within 16; C/D col
    const int kc   = lane >> 4;          // k-chunk; C/D row group
    const int n0   = nt * 64 + wv * 16;

    const float* xrow = x + ((long)bt * NN + n0 + r) * FIN;

    f32x4 acc[4] = {{0,0,0,0},{0,0,0,0},{0,0,0,0},{0,0,0,0}};

#pragma unroll
    for (int ks = 0; ks < 4; ++ks) {
        f32x4 xa = __builtin_nontemporal_load((const f32x4*)&xrow[ks * 32 + kc * 8]);
        f32x4 xb = __builtin_nontemporal_load((const f32x4*)&xrow[ks * 32 + kc * 8 + 4]);
        float xv[8] = {xa[0], xa[1], xa[2], xa[3], xb[0], xb[1], xb[2], xb[3]};
        bf16x8 Ahi, Alo;
#pragma unroll
        for (int e = 0; e < 8; ++e) {
            uint b = __float_as_uint(xv[e]);
            float hf = __uint_as_float(b & 0xFFFF0000u);
            Ahi[e] = (short)(b >> 16);
            float rr = xv[e] - hf;                       // exact (Sterbenz)
            Alo[e] = (short)(__float_as_uint(rr) >> 16); // trunc
        }
#pragma unroll
        for (int g = 0; g < 4; ++g) {
            const int wo = (g * 16 + r) * FIN + ks * 32 + kc * 8;
            bf16x8 Bhi = *(const bf16x8*)&Whi[wo];
            bf16x8 Blo = *(const bf16x8*)&Wlo[wo];
            acc[g] = __builtin_amdgcn_mfma_f32_16x16x32_bf16(Ahi, Bhi, acc[g], 0, 0, 0);
            acc[g] = __builtin_amdgcn_mfma_f32_16x16x32_bf16(Alo, Bhi, acc[g], 0, 0, 0);
            acc[g] = __builtin_amdgcn_mfma_f32_16x16x32_bf16(Ahi, Blo, acc[g], 0, 0, 0);
        }
    }

    float a1g[4], a2g[4];
#pragma unroll
    for (int g = 0; g < 4; ++g) {
        a1g[g] = a[g * 16 + r];
        a2g[g] = a[FOUT + g * 16 + r];
    }
    f32x4 s1v = {0,0,0,0}, s2v = {0,0,0,0};
#pragma unroll
    for (int g = 0; g < 4; ++g)
#pragma unroll
        for (int reg = 0; reg < 4; ++reg) {
            s1v[reg] += acc[g][reg] * a1g[g];
            s2v[reg] += acc[g][reg] * a2g[g];
        }
#pragma unroll
    for (int off = 8; off; off >>= 1)
#pragma unroll
        for (int reg = 0; reg < 4; ++reg) {
            s1v[reg] += __shfl_down(s1v[reg], off, 16);
            s2v[reg] += __shfl_down(s2v[reg], off, 16);
        }
    if (r == 0) {
        float4 o1 = make_float4(s1v[0], s1v[1], s1v[2], s1v[3]);
        float4 o2 = make_float4(s2v[0], s2v[1], s2v[2], s2v[3]);
        *(float4*)&srcv[bt * NN + n0 + kc * 4] = o1;
        *(float4*)&dstv[bt * NN + n0 + kc * 4] = o2;
    }

#pragma unroll
    for (int g = 0; g < 4; ++g) {
        uint2 pk;
        pk.x = (uint)f2bf(acc[g][0]) | ((uint)f2bf(acc[g][1]) << 16);
        pk.y = (uint)f2bf(acc[g][2]) | ((uint)f2bf(acc[g][3]) << 16);
        *(uint2*)&ht[(long)bt * (FOUT * NN) + (g * 16 + r) * NN + n0 + kc * 4] = pk;
    }
}

// 8 packed cd ushorts + dst -> A-fragment; pack via v_perm (trunc semantics).
static __device__ inline bf16x8 make_afrag(uint4 c, float4 d0, float4 d1, float si) {
    float dv[8] = {d0.x, d0.y, d0.z, d0.w, d1.x, d1.y, d1.z, d1.w};
    uint  cw[4] = {c.x, c.y, c.z, c.w};
    union { uint u[4]; bf16x8 v; } A;
#pragma unroll
    for (int q = 0; q < 4; ++q) {
        uint u = cw[q];
        float c0 = __uint_as_float((u << 16) & 0xFFFE0000u);
        float c1 = __uint_as_float(u & 0xFFFE0000u);
        float s0 = si + dv[2 * q],     lr0 = fmaxf(s0, 0.01f * s0);
        float s1 = si + dv[2 * q + 1], lr1 = fmaxf(s1, 0.01f * s1);
        float p0 = __builtin_amdgcn_exp2f(c0 * lr0);
        float p1 = __builtin_amdgcn_exp2f(c1 * lr1);
        p0 = (u & 1u)       ? p0 : 0.f;
        p1 = (u & 0x10000u) ? p1 : 0.f;
        // D = p1.hi16 : p0.hi16  (bf16 truncation, 1 instr)
        A.u[q] = __builtin_amdgcn_perm(__float_as_uint(p1), __float_as_uint(p0),
                                       0x07060302u);
    }
    return A.v;
}

// ---------- B: fused att + bf16 MFMA PV — 2-phase pipeline, global_load_lds ----
// grid 1024: bid = it*128 + bt => XCD = bt%8. 4 waves x 16 rows; LDS = 2 x 16KB
// quarter buffers (dbuf) + 2KB dst = 34.8KB -> 4 blocks/CU.
// Catalog 2-phase template: per quarter qt, FIRST issue next quarter's
// global_load_lds (4 instr/thread, no VGPR round-trip; swizzle on the SOURCE
// address, linear LDS dest — G21) + next cd loads, THEN compute quarter qt
// (make_afrag + 20 MFMA + swizzled ds_read_b128), then ONE __syncthreads()
// (its vmcnt(0) drains staging that already completed under the compute).
__global__ __launch_bounds__(256, 4)
void k_attn(const ushort* __restrict__ ht, const float* __restrict__ srcv,
            const float* __restrict__ dstv, const ushort* __restrict__ cds,
            float* __restrict__ out) {
    __shared__ ushort hs[2][64 * 128];   // quarter: [o][16 granules of 8 j]
    __shared__ float dst_s[NN];

    const int t    = threadIdx.x;
    const int bid  = blockIdx.x;
    const int bt   = bid & 127;
    const int it   = bid >> 7;
    const int i0   = it << 6;
    const int lane = t & 63;
    const int wv   = t >> 6;             // 0..3
    const int r16  = lane & 15;
    const int kc   = lane >> 4;          // 0..3
    const int koff = kc * 8;
    const int xr   = r16 & 7;

    const int ri = i0 + wv * 16 + r16;   // my A-row
    const float si = srcv[bt * NN + ri];
    // swizzled cd: 16 blocks of 512 ushorts per (it,wv); block f: +(f<<9)+lane*8
    const ushort* cdb = cds + (((it * 4 + wv) * 2) << 12) + (lane << 3);
    const ushort* htb = ht + (long)bt * (FOUT * NN);

    // per-thread staging source pieces (granule idx = q*256 + t)
    const int so  = t >> 4;              // row contribution within q-block
    const int sgs = t & 15;              // swizzled granule within row

    for (int q = t; q < NN; q += 256) dst_s[q] = dstv[bt * NN + q];

    f32x4 ac0 = {0,0,0,0}, ac1 = {0,0,0,0}, ac2 = {0,0,0,0}, ac3 = {0,0,0,0},
          acd = {0,0,0,0};
    bf16x8 ones;
#pragma unroll
    for (int j = 0; j < 8; ++j) ones[j] = (short)0x3F80;   // bf16 1.0

    uint4 cdc[4], cdn[4];
#pragma unroll
    for (int f = 0; f < 4; ++f) cdc[f] = *(const uint4*)&cdb[f << 9];

    // prologue: stage quarter 0 into buf 0
#pragma unroll
    for (int q = 0; q < 4; ++q) {
        int idx = q * 256 + t;
        int o = idx >> 4, gs = idx & 15;
        gll16(htb + (o << 9) + ((gs ^ (o & 7)) << 3),
              &hs[0][(q * 256 + (t & 0xC0)) * 8]);
    }
    __syncthreads();

#pragma unroll
    for (int qt = 0; qt < 4; ++qt) {
        const int cur = qt & 1;

        // phase A: issue next quarter's staging + cd (fly under compute)
        if (qt < 3) {
#pragma unroll
            for (int f = 0; f < 4; ++f)
                cdn[f] = *(const uint4*)&cdb[(4 * (qt + 1) + f) << 9];
#pragma unroll
            for (int q = 0; q < 4; ++q) {
                int idx = q * 256 + t;
                int o = idx >> 4, gs = idx & 15;
                gll16(htb + (o << 9) + ((qt + 1) << 7) + ((gs ^ (o & 7)) << 3),
                      &hs[cur ^ 1][(q * 256 + (t & 0xC0)) * 8]);
            }
        }

        // phase B: compute quarter qt from buf[cur]
#pragma unroll
        for (int j2 = 0; j2 < 2; ++j2) {
            const int jb = qt * 128 + j2 * 64;
            float4 d00 = *(float4*)&dst_s[jb + koff];
            float4 d01 = *(float4*)&dst_s[jb + koff + 4];
            float4 d10 = *(float4*)&dst_s[jb + 32 + koff];
            float4 d11 = *(float4*)&dst_s[jb + 32 + koff + 4];

            bf16x8 A0 = make_afrag(cdc[2 * j2],     d00, d01, si);   // s2 = 0
            bf16x8 A1 = make_afrag(cdc[2 * j2 + 1], d10, d11, si);   // s2 = 1

#pragma unroll
            for (int s2 = 0; s2 < 2; ++s2) {
                bf16x8 A = s2 ? A1 : A0;
                const int g = j2 * 8 + s2 * 4 + kc;          // quarter granule
                const int cs = ((g ^ xr) << 3);
                bf16x8 b0 = *(bf16x8*)&hs[cur][(( 0 + r16) << 7) + cs];
                bf16x8 b1 = *(bf16x8*)&hs[cur][((16 + r16) << 7) + cs];
                bf16x8 b2 = *(bf16x8*)&hs[cur][((32 + r16) << 7) + cs];
                bf16x8 b3 = *(bf16x8*)&hs[cur][((48 + r16) << 7) + cs];
                __builtin_amdgcn_s_setprio(1);
                ac0 = __builtin_amdgcn_mfma_f32_16x16x32_bf16(A, b0, ac0, 0, 0, 0);
                ac1 = __builtin_amdgcn_mfma_f32_16x16x32_bf16(A, b1, ac1, 0, 0, 0);
                ac2 = __builtin_amdgcn_mfma_f32_16x16x32_bf16(A, b2, ac2, 0, 0, 0);
                ac3 = __builtin_amdgcn_mfma_f32_16x16x32_bf16(A, b3, ac3, 0, 0, 0);
                acd = __builtin_amdgcn_mfma_f32_16x16x32_bf16(A, ones, acd, 0, 0, 0);
                __builtin_amdgcn_s_setprio(0);
            }
        }

        __syncthreads();   // drains staging (already landed) + joins waves
#pragma unroll
        for (int f = 0; f < 4; ++f) cdc[f] = cdn[f];
    }

    // epilogue: C/D col=r16 (o within g*16), row=kc*4+reg (i within wave's 16)
    float* ob = out + ((long)bt * NN + i0 + wv * 16) * FOUT;
#pragma unroll
    for (int reg = 0; reg < 4; ++reg) {
        float inv = 1.0f / acd[reg];
        const int rw = (kc * 4 + reg) * FOUT + r16;
        __builtin_nontemporal_store(ac0[reg] * inv, &ob[rw +  0]);
        __builtin_nontemporal_store(ac1[reg] * inv, &ob[rw + 16]);
        __builtin_nontemporal_store(ac2[reg] * inv, &ob[rw + 32]);
        __builtin_nontemporal_store(ac3[reg] * inv, &ob[rw + 48]);
    }
}

extern "C" void kernel_launch(void* const* d_in, const int* in_sizes, int n_in,
                              void* d_out, int out_size, void* d_ws, size_t ws_size,
                              hipStream_t stream) {
    const float* x      = (const float*)d_in[0];
    const float* W      = (const float*)d_in[1];
    const float* a      = (const float*)d_in[2];
    const int*   adj    = (const int*)d_in[3];
    const float* adj_we = (const float*)d_in[4];
    float* out = (float*)d_out;

    ushort* Whi  = (ushort*)d_ws;                      // 8192 bf16
    ushort* Wlo  = Whi + FOUT * FIN;                   // 8192 bf16
    ushort* ht   = Wlo + FOUT * FIN;                   // 128*64*512 bf16
    float*  srcv = (float*)(ht + BTOT * FOUT * NN);    // 65536 fp32
    float*  dstv = srcv + BTOT * NN;                   // 65536 fp32
    ushort* cdsw = (ushort*)(dstv + BTOT * NN);        // 262144 ushorts (swizzled)

    hipLaunchKernelGGL(k_prep, dim3(288), dim3(256), 0, stream,
                       W, adj, adj_we, Whi, Wlo, cdsw);
    hipLaunchKernelGGL(k_feat, dim3(1024), dim3(256), 0, stream,
                       x, Whi, Wlo, a, ht, srcv, dstv);
    hipLaunchKernelGGL(k_attn, dim3(1024), dim3(256), 0, stream,
                       ht, srcv, dstv, cdsw, out);
}